// Round 5
// baseline (466.798 us; speedup 1.0000x reference)
//
#include <hip/hip_runtime.h>
#include <float.h>

// Problem constants: x (2,128,64,64) fp32, w (256,256) fp32, b (256,) fp32
// out (2,256,64,64) fp32. K=9 nearest neighbors on normalized features.
constexpr int CB = 2;      // batch
constexpr int CC = 128;    // channels
constexpr int CN = 4096;   // points (64*64)
constexpr int CO2 = 512;   // P(256) + Q(256) packed weight columns

// ---- workspace layout (float offsets), total ~17.1 MB ----
constexpr size_t OFF_XN = 0;                                  // [B][C][N] normalized x
constexpr size_t OFF_SQ = OFF_XN + (size_t)CB * CC * CN;      // [B][N] sum(xn^2)
constexpr size_t OFF_RN = OFF_SQ + (size_t)CB * CN;           // [B][N] norm (x = xn*rn)
constexpr size_t OFF_WT = OFF_RN + (size_t)CB * CN;           // [C][512] (W1-W2 | W2)^T
constexpr size_t OFF_Q  = OFF_WT + (size_t)CC * CO2;          // [B][N][256] Q = W2^T x
constexpr size_t OFF_PV = OFF_Q  + (size_t)CB * CN * 256;     // [B][N][8][9] vals
constexpr size_t OFF_PJ = OFF_PV + (size_t)CB * CN * 72;      // [B][N][8][9] idx (int)
constexpr size_t OFF_NN = OFF_PJ + (size_t)CB * CN * 72;      // [B][N][9] final idx (int)

// top-9 sorted-desc insert; comparator matches jax.lax.top_k tie-break:
// better == (v > cur) || (v == cur && idx < cur_idx). Static indexing only.
__device__ __forceinline__ void topk_insert(float (&sv)[9], int (&sj)[9], float v, int jg) {
    if ((v > sv[8]) || (v == sv[8] && jg < sj[8])) {
        bool bb[9];
#pragma unroll
        for (int k = 0; k < 9; ++k) bb[k] = (v > sv[k]) || (v == sv[k] && jg < sj[k]);
#pragma unroll
        for (int k = 8; k >= 1; --k) {
            sv[k] = bb[k - 1] ? sv[k - 1] : (bb[k] ? v : sv[k]);
            sj[k] = bb[k - 1] ? sj[k - 1] : (bb[k] ? jg : sj[k]);
        }
        sv[0] = bb[0] ? v : sv[0];
        sj[0] = bb[0] ? jg : sj[0];
    }
}

// ---- Kernel A: normalize; xn = x * rsqrt(sum x^2 + eps); sq = sum xn^2; rn = sqrt(ss+eps)
__global__ __launch_bounds__(256) void prep_kernel(const float* __restrict__ x,
                                                   float* __restrict__ xn,
                                                   float* __restrict__ sqv,
                                                   float* __restrict__ rnv) {
    __shared__ float XT[128][64];
    __shared__ float red[4][64];
    __shared__ float invl[64];
    const int b = blockIdx.y, n0 = blockIdx.x * 64;
    const int tid = threadIdx.x;
    const int nl = tid & 63, c0 = tid >> 6;
#pragma unroll 4
    for (int cc = 0; cc < 32; ++cc) {
        int c = cc * 4 + c0;
        XT[c][nl] = x[((size_t)(b * 128 + c)) * 4096 + n0 + nl];
    }
    __syncthreads();
    {
        float acc = 0.f;
#pragma unroll 4
        for (int cc = 0; cc < 32; ++cc) { float v = XT[c0 * 32 + cc][nl]; acc += v * v; }
        red[c0][nl] = acc;
    }
    __syncthreads();
    if (tid < 64) {
        float ss = red[0][tid] + red[1][tid] + red[2][tid] + red[3][tid] + 1e-12f;
        float sr = sqrtf(ss);
        invl[tid] = 1.0f / sr;
        rnv[b * 4096 + n0 + tid] = sr;
    }
    __syncthreads();
    {
        float acc = 0.f;
        float iv = invl[nl];
#pragma unroll 4
        for (int cc = 0; cc < 32; ++cc) {
            int c = cc * 4 + c0;
            float v = XT[c][nl] * iv;
            xn[((size_t)(b * 128 + c)) * 4096 + n0 + nl] = v;
            acc += v * v;
        }
        red[c0][nl] = acc;
    }
    __syncthreads();
    if (tid < 64) {
        sqv[b * 4096 + n0 + tid] = red[0][tid] + red[1][tid] + red[2][tid] + red[3][tid];
    }
}

// ---- Kernel W: WT[c][o] = (o<256) ? w[o][c]-w[o][128+c] : w[o-256][128+c] ----
__global__ __launch_bounds__(256) void wprep_kernel(const float* __restrict__ w,
                                                    float* __restrict__ wt) {
    int id = blockIdx.x * 256 + threadIdx.x;   // 65536 = 128*512
    int c = id >> 9, o = id & 511;
    float v;
    if (o < 256) v = w[o * 256 + c] - w[o * 256 + 128 + c];
    else         v = w[(o - 256) * 256 + 128 + c];
    wt[c * 512 + o] = v;
}

// ---- Kernel B v4: fused Gram + top-9, 8x8 register fragments, split B-frag ----
// grid (8 col-splits, 64 row-tiles, B). Block: 64 rows x 512 cols (2 J-tiles of 256).
// Per-thread frag: rows ty*8..+7, cols {tx*4..+3} U {128+tx*4..+3}.
// launch_bounds(256,2): cap 256 arch VGPRs -> acc[8][8] stays in VGPRs.
// (256,4) spilled acc to scratch (r3: 47MB HBM fetch); (256,3) put acc in AGPRs
// with v_accvgpr copies around every FMA (r4: VALU-issue 2.3x the FMA floor).
// Occupancy is deterministically 2 blocks/CU; grid 1024 = 2 clean rounds.
__global__ __launch_bounds__(256, 2) void knn_kernel(const float* __restrict__ xn,
                                                     const float* __restrict__ sqv,
                                                     float* __restrict__ pv,
                                                     int* __restrict__ pj) {
    __shared__ float lds[10240];               // 40960 B
    float* As  = lds;                          // [32][64]   GEMM phase
    float* Bs  = lds + 2048;                   // [32][256]  GEMM phase
    float* Sf  = lds;                          // [32][260]  score overlay (8320 floats)
    float* SQJ = lds + 9216;                   // [256] sq_j for current J-tile
    float* MV  = lds;                          // [256][9]   merge overlay
    int*   MJ  = (int*)(lds + 2304);           // [256][9]

    const int b  = blockIdx.z;
    const int i0 = blockIdx.y * 64;
    const int js = blockIdx.x;                 // 0..7, cols js*512 .. +511
    const int tid = threadIdx.x;
    const int tx = tid & 31, ty = tid >> 5;    // frag: rows ty*8+, cols tx*4+ / 128+tx*4+
    const int sr = tid >> 2, g = tid & 3;      // scan: row owner, col-group

    const float sqi = sqv[b * 4096 + i0 + sr];
    float sv[9]; int sj[9];
#pragma unroll
    for (int k = 0; k < 9; ++k) { sv[k] = -FLT_MAX; sj[k] = 0x7fffffff; }

    for (int jt = 0; jt < 2; ++jt) {
        const int j0 = js * 512 + jt * 256;
        float acc[8][8];
#pragma unroll
        for (int i = 0; i < 8; ++i)
#pragma unroll
            for (int j = 0; j < 8; ++j) acc[i][j] = 0.f;

        for (int ch = 0; ch < 4; ++ch) {
            __syncthreads();                   // prev readers of As/Bs/Sf done
            {   // stage As[32][64]: 2 float4/thread
                const int cl = tid >> 4, i4 = (tid & 15) * 4;
                const size_t base = ((size_t)(b * 128 + ch * 32)) * 4096 + i0;
                *(float4*)&As[cl * 64 + i4] =
                    *(const float4*)&xn[base + (size_t)cl * 4096 + i4];
                *(float4*)&As[(cl + 16) * 64 + i4] =
                    *(const float4*)&xn[base + (size_t)(cl + 16) * 4096 + i4];
            }
            {   // stage Bs[32][256]: 8 float4/thread
                const int cl = tid >> 6, j4 = (tid & 63) * 4;
                const size_t base = ((size_t)(b * 128 + ch * 32)) * 4096 + j0;
#pragma unroll
                for (int u = 0; u < 8; ++u)
                    *(float4*)&Bs[(cl + u * 4) * 256 + j4] =
                        *(const float4*)&xn[base + (size_t)(cl + u * 4) * 4096 + j4];
            }
            __syncthreads();
#pragma unroll 2
            for (int c = 0; c < 32; ++c) {
                const float4 a0 = *(const float4*)&As[c * 64 + ty * 8];
                const float4 a1 = *(const float4*)&As[c * 64 + ty * 8 + 4];
                const float4 b0 = *(const float4*)&Bs[c * 256 + tx * 4];        // 16B stride
                const float4 b1 = *(const float4*)&Bs[c * 256 + 128 + tx * 4];  // 16B stride
                const float ar[8] = {a0.x, a0.y, a0.z, a0.w, a1.x, a1.y, a1.z, a1.w};
                const float br[8] = {b0.x, b0.y, b0.z, b0.w, b1.x, b1.y, b1.z, b1.w};
#pragma unroll
                for (int i = 0; i < 8; ++i)
#pragma unroll
                    for (int j = 0; j < 8; ++j) acc[i][j] = fmaf(ar[i], br[j], acc[i][j]);
            }
        }
        __syncthreads();                       // all FMA done; Bs region reusable
        if (tid < 64)                          // stage sq_j (lives above score buffer)
            *(float4*)&SQJ[tid * 4] = *(const float4*)&sqv[b * 4096 + j0 + tid * 4];

        for (int h = 0; h < 2; ++h) {          // score rows h*32..h*32+31
            if ((ty >> 2) == h) {
                const int lrb = (ty & 3) * 8;
#pragma unroll
                for (int r = 0; r < 8; ++r) {
                    *(float4*)&Sf[(lrb + r) * 260 + tx * 4] =
                        make_float4(acc[r][0], acc[r][1], acc[r][2], acc[r][3]);
                    *(float4*)&Sf[(lrb + r) * 260 + 128 + tx * 4] =
                        make_float4(acc[r][4], acc[r][5], acc[r][6], acc[r][7]);
                }
            }
            __syncthreads();                   // scores + sqj visible
            if ((sr >> 5) == h) {
                const float* row = &Sf[(sr & 31) * 260];
#pragma unroll 8
                for (int m = 0; m < 64; ++m) {
                    const int jl = m * 4 + g;  // conflict-free interleave
                    const float full = (2.0f * row[jl] - sqi) - SQJ[jl];
                    topk_insert(sv, sj, full, j0 + jl);
                }
            }
            __syncthreads();                   // scan done before overwrite
        }
    }
    // in-block merge: 4 col-group lists per row -> 1 list, write split js
#pragma unroll
    for (int k = 0; k < 9; ++k) { MV[tid * 9 + k] = sv[k]; MJ[tid * 9 + k] = sj[k]; }
    __syncthreads();
    if (tid < 64) {
        float mv[9]; int mj[9];
#pragma unroll
        for (int k = 0; k < 9; ++k) { mv[k] = -FLT_MAX; mj[k] = 0x7fffffff; }
        for (int q2 = 0; q2 < 4; ++q2)
            for (int k = 0; k < 9; ++k)
                topk_insert(mv, mj, MV[(tid * 4 + q2) * 9 + k], MJ[(tid * 4 + q2) * 9 + k]);
        const int base = ((b * 4096 + i0 + tid) * 8 + js) * 9;
#pragma unroll
        for (int k = 0; k < 9; ++k) { pv[base + k] = mv[k]; pj[base + k] = mj[k]; }
    }
}

// ---- Kernel M: merge 8 split-lists -> final 9 indices per row ----
__global__ __launch_bounds__(256) void merge_kernel(const float* __restrict__ pv,
                                                    const int* __restrict__ pj,
                                                    int* __restrict__ nn) {
    int t = blockIdx.x * 256 + threadIdx.x;   // 0..8191 = b*4096+n
    float sv[9]; int sj[9];
#pragma unroll
    for (int k = 0; k < 9; ++k) { sv[k] = -FLT_MAX; sj[k] = 0x7fffffff; }
    int base = t * 72;
    for (int s = 0; s < 72; ++s) topk_insert(sv, sj, pv[base + s], pj[base + s]);
#pragma unroll
    for (int k = 0; k < 9; ++k) nn[t * 9 + k] = sj[k];
}

// ---- Kernel C: P/Q GEMM. o' = o0+tx*4+j over 512 packed outputs.
// P (o'<256): out[b][o'][n] layout, float4 along n. Q (o'>=256): q[b][n][o'-256].
__global__ __launch_bounds__(256, 2) void pq_kernel(const float* __restrict__ xn,
                                                    const float* __restrict__ wt,
                                                    const float* __restrict__ rnv,
                                                    float* __restrict__ q,
                                                    float* __restrict__ out) {
    __shared__ float Xs[128][64];
    __shared__ float Ws[128][64];
    const int b = blockIdx.z;
    const int n0 = blockIdx.x * 64;
    const int o0 = blockIdx.y * 64;
    const int tid = threadIdx.x;
    {
        const int c4 = tid >> 4, j4 = (tid & 15) * 4;
#pragma unroll
        for (int cc = 0; cc < 8; ++cc) {
            int c = cc * 16 + c4;
            *(float4*)&Xs[c][j4] = *(const float4*)&xn[((size_t)(b * 128 + c)) * 4096 + n0 + j4];
            *(float4*)&Ws[c][j4] = *(const float4*)&wt[c * 512 + o0 + j4];
        }
    }
    __syncthreads();
    const int tx = tid & 15, ty = tid >> 4;
    float acc[4][4];
#pragma unroll
    for (int i = 0; i < 4; ++i)
#pragma unroll
        for (int j = 0; j < 4; ++j) acc[i][j] = 0.f;
#pragma unroll 4
    for (int c = 0; c < 128; ++c) {
        const float4 av = *(const float4*)&Xs[c][ty * 4];
        const float4 bv = *(const float4*)&Ws[c][tx * 4];
        const float ar[4] = {av.x, av.y, av.z, av.w};
        const float br[4] = {bv.x, bv.y, bv.z, bv.w};
#pragma unroll
        for (int i = 0; i < 4; ++i)
#pragma unroll
            for (int j = 0; j < 4; ++j) acc[i][j] = fmaf(ar[i], br[j], acc[i][j]);
    }
    const float4 rv = *(const float4*)&rnv[b * 4096 + n0 + ty * 4];
    if (o0 < 256) {
        // P -> d_out[b][o][n], contiguous along n within each thread
#pragma unroll
        for (int j = 0; j < 4; ++j) {
            float4 v = make_float4(acc[0][j] * rv.x, acc[1][j] * rv.y,
                                   acc[2][j] * rv.z, acc[3][j] * rv.w);
            *(float4*)&out[((size_t)(b * 256 + o0 + tx * 4 + j)) * 4096 + n0 + ty * 4] = v;
        }
    } else {
        const float rr[4] = {rv.x, rv.y, rv.z, rv.w};
#pragma unroll
        for (int i = 0; i < 4; ++i) {
            float4 v = make_float4(acc[i][0] * rr[i], acc[i][1] * rr[i],
                                   acc[i][2] * rr[i], acc[i][3] * rr[i]);
            *(float4*)&q[((size_t)(b * 4096 + n0 + ty * 4 + i)) * 256 + (o0 - 256) + tx * 4] = v;
        }
    }
}

// ---- Kernel D: out[b][o][n] = relu(P(out) + bias[o] + max_k Q[nn(n,k)][o]) in place ----
__global__ __launch_bounds__(256) void gather_kernel(const float* __restrict__ q,
                                                     const int* __restrict__ nn,
                                                     const float* __restrict__ bias,
                                                     float* __restrict__ out) {
    __shared__ int idx[32][9];
    const int b = blockIdx.y, n0 = blockIdx.x * 32;
    const int tid = threadIdx.x;
    for (int t = tid; t < 288; t += 256) {
        int pt = t / 9, k = t - pt * 9;
        idx[pt][k] = nn[(b * 4096 + n0 + pt) * 9 + k];
    }
    __syncthreads();
    const float bv = bias[tid];
    const size_t orow = ((size_t)(b * 256 + tid)) * 4096 + n0;
    float pvals[32];
#pragma unroll
    for (int u = 0; u < 8; ++u)
        *(float4*)&pvals[u * 4] = *(const float4*)&out[orow + u * 4];
    float val[32];
#pragma unroll
    for (int pt = 0; pt < 32; ++pt) {
        float m = -FLT_MAX;
#pragma unroll
        for (int k = 0; k < 9; ++k) {
            int j = idx[pt][k] & 4095;             // clamp: wild index -> wrong value, not fault
            m = fmaxf(m, q[((size_t)(b * 4096 + j)) * 256 + tid]);
        }
        float vv = pvals[pt] + bv + m;
        val[pt] = vv > 0.f ? vv : 0.f;
    }
#pragma unroll
    for (int u = 0; u < 8; ++u) {
        float4 v = make_float4(val[u * 4], val[u * 4 + 1], val[u * 4 + 2], val[u * 4 + 3]);
        *(float4*)&out[orow + u * 4] = v;
    }
}

extern "C" void kernel_launch(void* const* d_in, const int* in_sizes, int n_in,
                              void* d_out, int out_size, void* d_ws, size_t ws_size,
                              hipStream_t stream) {
    const float* x    = (const float*)d_in[0];
    const float* w    = (const float*)d_in[1];
    const float* bias = (const float*)d_in[2];
    float* ws = (float*)d_ws;
    float* xn = ws + OFF_XN;
    float* sq = ws + OFF_SQ;
    float* rn = ws + OFF_RN;
    float* wt = ws + OFF_WT;
    float* q  = ws + OFF_Q;
    float* pv = ws + OFF_PV;
    int*   pj = (int*)(ws + OFF_PJ);
    int*   nn = (int*)(ws + OFF_NN);
    float* out = (float*)d_out;

    prep_kernel  <<<dim3(64, 2),    256, 0, stream>>>(x, xn, sq, rn);
    wprep_kernel <<<dim3(256),      256, 0, stream>>>(w, wt);
    knn_kernel   <<<dim3(8, 64, 2), 256, 0, stream>>>(xn, sq, pv, pj);
    merge_kernel <<<dim3(32),       256, 0, stream>>>(pv, pj, nn);
    pq_kernel    <<<dim3(64, 8, 2), 256, 0, stream>>>(xn, wt, rn, q, out);
    gather_kernel<<<dim3(128, 2),   256, 0, stream>>>(q, nn, bias, out);
}

// Round 6
// 317.606 us; speedup vs baseline: 1.4697x; 1.4697x over previous
//
#include <hip/hip_runtime.h>
#include <float.h>

// Problem constants: x (2,128,64,64) fp32, w (256,256) fp32, b (256,) fp32
// out (2,256,64,64) fp32. K=9 nearest neighbors on normalized features.
constexpr int CB = 2;      // batch
constexpr int CC = 128;    // channels
constexpr int CN = 4096;   // points (64*64)
constexpr int CO2 = 512;   // P(256) + Q(256) packed weight columns

// ---- workspace layout (float offsets), total ~17.1 MB ----
constexpr size_t OFF_XN = 0;                                  // [B][C][N] normalized x
constexpr size_t OFF_SQ = OFF_XN + (size_t)CB * CC * CN;      // [B][N] sum(xn^2)
constexpr size_t OFF_RN = OFF_SQ + (size_t)CB * CN;           // [B][N] norm (x = xn*rn)
constexpr size_t OFF_WT = OFF_RN + (size_t)CB * CN;           // [C][512] (W1-W2 | W2)^T
constexpr size_t OFF_Q  = OFF_WT + (size_t)CC * CO2;          // [B][N][256] Q = W2^T x
constexpr size_t OFF_PV = OFF_Q  + (size_t)CB * CN * 256;     // [B][N][8][9] vals
constexpr size_t OFF_PJ = OFF_PV + (size_t)CB * CN * 72;      // [B][N][8][9] idx (int)
constexpr size_t OFF_NN = OFF_PJ + (size_t)CB * CN * 72;      // [B][N][9] final idx (int)

// top-9 sorted-desc insert; comparator matches jax.lax.top_k tie-break:
// better == (v > cur) || (v == cur && idx < cur_idx). Static indexing only.
__device__ __forceinline__ void topk_insert(float (&sv)[9], int (&sj)[9], float v, int jg) {
    if ((v > sv[8]) || (v == sv[8] && jg < sj[8])) {
        bool bb[9];
#pragma unroll
        for (int k = 0; k < 9; ++k) bb[k] = (v > sv[k]) || (v == sv[k] && jg < sj[k]);
#pragma unroll
        for (int k = 8; k >= 1; --k) {
            sv[k] = bb[k - 1] ? sv[k - 1] : (bb[k] ? v : sv[k]);
            sj[k] = bb[k - 1] ? sj[k - 1] : (bb[k] ? jg : sj[k]);
        }
        sv[0] = bb[0] ? v : sv[0];
        sj[0] = bb[0] ? jg : sj[0];
    }
}

// ---- Kernel A: normalize; xn = x * rsqrt(sum x^2 + eps); sq = sum xn^2; rn = sqrt(ss+eps)
__global__ __launch_bounds__(256) void prep_kernel(const float* __restrict__ x,
                                                   float* __restrict__ xn,
                                                   float* __restrict__ sqv,
                                                   float* __restrict__ rnv) {
    __shared__ float XT[128][64];
    __shared__ float red[4][64];
    __shared__ float invl[64];
    const int b = blockIdx.y, n0 = blockIdx.x * 64;
    const int tid = threadIdx.x;
    const int nl = tid & 63, c0 = tid >> 6;
#pragma unroll 4
    for (int cc = 0; cc < 32; ++cc) {
        int c = cc * 4 + c0;
        XT[c][nl] = x[((size_t)(b * 128 + c)) * 4096 + n0 + nl];
    }
    __syncthreads();
    {
        float acc = 0.f;
#pragma unroll 4
        for (int cc = 0; cc < 32; ++cc) { float v = XT[c0 * 32 + cc][nl]; acc += v * v; }
        red[c0][nl] = acc;
    }
    __syncthreads();
    if (tid < 64) {
        float ss = red[0][tid] + red[1][tid] + red[2][tid] + red[3][tid] + 1e-12f;
        float sr = sqrtf(ss);
        invl[tid] = 1.0f / sr;
        rnv[b * 4096 + n0 + tid] = sr;
    }
    __syncthreads();
    {
        float acc = 0.f;
        float iv = invl[nl];
#pragma unroll 4
        for (int cc = 0; cc < 32; ++cc) {
            int c = cc * 4 + c0;
            float v = XT[c][nl] * iv;
            xn[((size_t)(b * 128 + c)) * 4096 + n0 + nl] = v;
            acc += v * v;
        }
        red[c0][nl] = acc;
    }
    __syncthreads();
    if (tid < 64) {
        sqv[b * 4096 + n0 + tid] = red[0][tid] + red[1][tid] + red[2][tid] + red[3][tid];
    }
}

// ---- Kernel W: WT[c][o] = (o<256) ? w[o][c]-w[o][128+c] : w[o-256][128+c] ----
__global__ __launch_bounds__(256) void wprep_kernel(const float* __restrict__ w,
                                                    float* __restrict__ wt) {
    int id = blockIdx.x * 256 + threadIdx.x;   // 65536 = 128*512
    int c = id >> 9, o = id & 511;
    float v;
    if (o < 256) v = w[o * 256 + c] - w[o * 256 + 128 + c];
    else         v = w[(o - 256) * 256 + 128 + c];
    wt[c * 512 + o] = v;
}

// ---- Kernel B v6: fused Gram + top-9 ----
// r2's proven 4x4-frag dataflow (88 VGPR, identical accumulation order ->
// bit-identical neighbor scores), with K-chunked staging: A[64][64]+B[64][64]
// per chunk = 33KB LDS -> 4 blocks/CU (16 waves, 2x r2's occupancy).
// grid (8 col-splits, 64 row-tiles, B) = 1024 blocks = exactly 4/CU.
// r3-r5 lesson: >=64-float acc trips the allocator into AGPR/scratch forms;
// 16-float acc + (256,4) cap (128 VGPR > 88 needed) is the stable point.
__global__ __launch_bounds__(256, 4) void knn_kernel(const float* __restrict__ xn,
                                                     const float* __restrict__ sqv,
                                                     float* __restrict__ pv,
                                                     int* __restrict__ pj) {
    __shared__ float lds[8256];                // 33,024 B
    float* As  = lds;                          // [64c][64i] chunk
    float* Bs  = lds + 4096;                   // [64c][64j] chunk
    float* Sf  = lds;                          // scores [64][68] overlay (4352 floats)
    float* SQJ = lds + 8192;                   // [64] sq_j for current tile
    float* MV  = lds;                          // [256][9] merge overlay
    int*   MJ  = (int*)(lds + 2304);           // [256][9]

    const int b  = blockIdx.z;
    const int i0 = blockIdx.y * 64;
    const int js = blockIdx.x;                 // 0..7, cols js*512 .. +511
    const int tid = threadIdx.x;
    const int tx = tid & 15, ty = tid >> 4;    // frag: rows ty*4.., cols tx*4..
    const int sr = tid >> 2, g = tid & 3;      // scan: row owner, col-group

    const float sqi = sqv[b * 4096 + i0 + sr];
    float sv[9]; int sj[9];
#pragma unroll
    for (int k = 0; k < 9; ++k) { sv[k] = -FLT_MAX; sj[k] = 0x7fffffff; }

    // staging map: 4 threads per c-row, each thread 4 float4 (64 floats/row)
    const int scl = tid >> 2;                  // c-line 0..63
    const int sq4 = (tid & 3) * 16;            // starting float within row

    for (int t = 0; t < 8; ++t) {              // 8 j-tiles of 64 cols
        const int jt = js * 512 + t * 64;
        float acc[4][4];
#pragma unroll
        for (int i = 0; i < 4; ++i)
#pragma unroll
            for (int j = 0; j < 4; ++j) acc[i][j] = 0.f;

        for (int ch = 0; ch < 2; ++ch) {       // K chunks: c = ch*64 .. +63
            __syncthreads();                   // prev readers of As/Bs/Sf done
            {
                const size_t gbase = ((size_t)(b * 128 + ch * 64 + scl)) * 4096;
#pragma unroll
                for (int u = 0; u < 4; ++u) {
                    *(float4*)&As[scl * 64 + sq4 + u * 4] =
                        *(const float4*)&xn[gbase + i0 + sq4 + u * 4];
                    *(float4*)&Bs[scl * 64 + sq4 + u * 4] =
                        *(const float4*)&xn[gbase + jt + sq4 + u * 4];
                }
            }
            __syncthreads();
#pragma unroll 4
            for (int c = 0; c < 64; ++c) {
                const float4 av = *(const float4*)&As[c * 64 + ty * 4];
                const float4 bv = *(const float4*)&Bs[c * 64 + tx * 4];
                const float ar[4] = {av.x, av.y, av.z, av.w};
                const float br[4] = {bv.x, bv.y, bv.z, bv.w};
#pragma unroll
                for (int i = 0; i < 4; ++i)
#pragma unroll
                    for (int j = 0; j < 4; ++j) acc[i][j] = fmaf(ar[i], br[j], acc[i][j]);
            }
        }
        __syncthreads();                       // all FMA done; overlay As/Bs with scores
#pragma unroll
        for (int i = 0; i < 4; ++i) {
            float4 v = make_float4(acc[i][0], acc[i][1], acc[i][2], acc[i][3]);
            *(float4*)&Sf[(ty * 4 + i) * 68 + tx * 4] = v;   // stride 68
        }
        if (tid < 16)
            *(float4*)&SQJ[tid * 4] = *(const float4*)&sqv[b * 4096 + jt + tid * 4];
        __syncthreads();                       // scores + sqj visible
#pragma unroll 8
        for (int m = 0; m < 16; ++m) {
            const int jl = m * 4 + g;          // conflict-free interleave
            const float full = (2.0f * Sf[sr * 68 + jl] - sqi) - SQJ[jl];
            topk_insert(sv, sj, full, jt + jl);
        }
        // next tile's first __syncthreads protects Sf until scan done
    }
    __syncthreads();
    // in-block merge: 4 col-group lists per row -> 1 list, write split js
#pragma unroll
    for (int k = 0; k < 9; ++k) { MV[tid * 9 + k] = sv[k]; MJ[tid * 9 + k] = sj[k]; }
    __syncthreads();
    if (tid < 64) {
        float mv[9]; int mj[9];
#pragma unroll
        for (int k = 0; k < 9; ++k) { mv[k] = -FLT_MAX; mj[k] = 0x7fffffff; }
        for (int q2 = 0; q2 < 4; ++q2)
            for (int k = 0; k < 9; ++k)
                topk_insert(mv, mj, MV[(tid * 4 + q2) * 9 + k], MJ[(tid * 4 + q2) * 9 + k]);
        const int base = ((b * 4096 + i0 + tid) * 8 + js) * 9;
#pragma unroll
        for (int k = 0; k < 9; ++k) { pv[base + k] = mv[k]; pj[base + k] = mj[k]; }
    }
}

// ---- Kernel M: merge 8 split-lists -> final 9 indices per row ----
__global__ __launch_bounds__(256) void merge_kernel(const float* __restrict__ pv,
                                                    const int* __restrict__ pj,
                                                    int* __restrict__ nn) {
    int t = blockIdx.x * 256 + threadIdx.x;   // 0..8191 = b*4096+n
    float sv[9]; int sj[9];
#pragma unroll
    for (int k = 0; k < 9; ++k) { sv[k] = -FLT_MAX; sj[k] = 0x7fffffff; }
    int base = t * 72;
    for (int s = 0; s < 72; ++s) topk_insert(sv, sj, pv[base + s], pj[base + s]);
#pragma unroll
    for (int k = 0; k < 9; ++k) nn[t * 9 + k] = sj[k];
}

// ---- Kernel C: P/Q GEMM. o' = o0+tx*4+j over 512 packed outputs.
// P (o'<256): out[b][o'][n] layout, float4 along n. Q (o'>=256): q[b][n][o'-256].
__global__ __launch_bounds__(256, 2) void pq_kernel(const float* __restrict__ xn,
                                                    const float* __restrict__ wt,
                                                    const float* __restrict__ rnv,
                                                    float* __restrict__ q,
                                                    float* __restrict__ out) {
    __shared__ float Xs[128][64];
    __shared__ float Ws[128][64];
    const int b = blockIdx.z;
    const int n0 = blockIdx.x * 64;
    const int o0 = blockIdx.y * 64;
    const int tid = threadIdx.x;
    {
        const int c4 = tid >> 4, j4 = (tid & 15) * 4;
#pragma unroll
        for (int cc = 0; cc < 8; ++cc) {
            int c = cc * 16 + c4;
            *(float4*)&Xs[c][j4] = *(const float4*)&xn[((size_t)(b * 128 + c)) * 4096 + n0 + j4];
            *(float4*)&Ws[c][j4] = *(const float4*)&wt[c * 512 + o0 + j4];
        }
    }
    __syncthreads();
    const int tx = tid & 15, ty = tid >> 4;
    float acc[4][4];
#pragma unroll
    for (int i = 0; i < 4; ++i)
#pragma unroll
        for (int j = 0; j < 4; ++j) acc[i][j] = 0.f;
#pragma unroll 4
    for (int c = 0; c < 128; ++c) {
        const float4 av = *(const float4*)&Xs[c][ty * 4];
        const float4 bv = *(const float4*)&Ws[c][tx * 4];
        const float ar[4] = {av.x, av.y, av.z, av.w};
        const float br[4] = {bv.x, bv.y, bv.z, bv.w};
#pragma unroll
        for (int i = 0; i < 4; ++i)
#pragma unroll
            for (int j = 0; j < 4; ++j) acc[i][j] = fmaf(ar[i], br[j], acc[i][j]);
    }
    const float4 rv = *(const float4*)&rnv[b * 4096 + n0 + ty * 4];
    if (o0 < 256) {
        // P -> d_out[b][o][n], contiguous along n within each thread
#pragma unroll
        for (int j = 0; j < 4; ++j) {
            float4 v = make_float4(acc[0][j] * rv.x, acc[1][j] * rv.y,
                                   acc[2][j] * rv.z, acc[3][j] * rv.w);
            *(float4*)&out[((size_t)(b * 256 + o0 + tx * 4 + j)) * 4096 + n0 + ty * 4] = v;
        }
    } else {
        const float rr[4] = {rv.x, rv.y, rv.z, rv.w};
#pragma unroll
        for (int i = 0; i < 4; ++i) {
            float4 v = make_float4(acc[i][0] * rr[i], acc[i][1] * rr[i],
                                   acc[i][2] * rr[i], acc[i][3] * rr[i]);
            *(float4*)&q[((size_t)(b * 4096 + n0 + ty * 4 + i)) * 256 + (o0 - 256) + tx * 4] = v;
        }
    }
}

// ---- Kernel D: out[b][o][n] = relu(P(out) + bias[o] + max_k Q[nn(n,k)][o]) in place ----
__global__ __launch_bounds__(256) void gather_kernel(const float* __restrict__ q,
                                                     const int* __restrict__ nn,
                                                     const float* __restrict__ bias,
                                                     float* __restrict__ out) {
    __shared__ int idx[32][9];
    const int b = blockIdx.y, n0 = blockIdx.x * 32;
    const int tid = threadIdx.x;
    for (int t = tid; t < 288; t += 256) {
        int pt = t / 9, k = t - pt * 9;
        idx[pt][k] = nn[(b * 4096 + n0 + pt) * 9 + k];
    }
    __syncthreads();
    const float bv = bias[tid];
    const size_t orow = ((size_t)(b * 256 + tid)) * 4096 + n0;
    float pvals[32];
#pragma unroll
    for (int u = 0; u < 8; ++u)
        *(float4*)&pvals[u * 4] = *(const float4*)&out[orow + u * 4];
    float val[32];
#pragma unroll
    for (int pt = 0; pt < 32; ++pt) {
        float m = -FLT_MAX;
#pragma unroll
        for (int k = 0; k < 9; ++k) {
            int j = idx[pt][k] & 4095;             // clamp: wild index -> wrong value, not fault
            m = fmaxf(m, q[((size_t)(b * 4096 + j)) * 256 + tid]);
        }
        float vv = pvals[pt] + bv + m;
        val[pt] = vv > 0.f ? vv : 0.f;
    }
#pragma unroll
    for (int u = 0; u < 8; ++u) {
        float4 v = make_float4(val[u * 4], val[u * 4 + 1], val[u * 4 + 2], val[u * 4 + 3]);
        *(float4*)&out[orow + u * 4] = v;
    }
}

extern "C" void kernel_launch(void* const* d_in, const int* in_sizes, int n_in,
                              void* d_out, int out_size, void* d_ws, size_t ws_size,
                              hipStream_t stream) {
    const float* x    = (const float*)d_in[0];
    const float* w    = (const float*)d_in[1];
    const float* bias = (const float*)d_in[2];
    float* ws = (float*)d_ws;
    float* xn = ws + OFF_XN;
    float* sq = ws + OFF_SQ;
    float* rn = ws + OFF_RN;
    float* wt = ws + OFF_WT;
    float* q  = ws + OFF_Q;
    float* pv = ws + OFF_PV;
    int*   pj = (int*)(ws + OFF_PJ);
    int*   nn = (int*)(ws + OFF_NN);
    float* out = (float*)d_out;

    prep_kernel  <<<dim3(64, 2),    256, 0, stream>>>(x, xn, sq, rn);
    wprep_kernel <<<dim3(256),      256, 0, stream>>>(w, wt);
    knn_kernel   <<<dim3(8, 64, 2), 256, 0, stream>>>(xn, sq, pv, pj);
    merge_kernel <<<dim3(32),       256, 0, stream>>>(pv, pj, nn);
    pq_kernel    <<<dim3(64, 8, 2), 256, 0, stream>>>(xn, wt, rn, q, out);
    gather_kernel<<<dim3(128, 2),   256, 0, stream>>>(q, nn, bias, out);
}